// Round 2
// baseline (1458.611 us; speedup 1.0000x reference)
//
#include <hip/hip_runtime.h>
#include <cstddef>

#define B_ 8
#define S_ 512
#define D_ 512
#define TS 8

// workspace float offsets
#define WS_BASES 0
#define WS_PES   131072
#define WS_BASED 262144
#define WS_PED   393216
#define WS_UD    524288                       // [B][D][32]
#define WS_ZD    (WS_UD + B_*D_*32)           // [B][D]
#define WS_US    (WS_ZD + B_*D_)              // [B][S][32]
#define WS_ZS    (WS_US + B_*S_*32)           // [B][S]
#define WS_ZERO_BASE WS_UD
#define WS_ZERO_F4   67584                    // (B*D*33 + B*S*33)/4 float4s

// output float offsets
#define HS_OFF 0
#define HD_OFF 131072
#define HE_OFF 262144

// ---------------- kernel 0: node projections + zero accumulators ----------------
__global__ __launch_bounds__(256)
void k0_nodes(const float* __restrict__ x_s, const float* __restrict__ x_d,
              const float* __restrict__ W_ss, const float* __restrict__ b_ss,
              const float* __restrict__ W_dd, const float* __restrict__ b_dd,
              const float* __restrict__ W_es, const float* __restrict__ W_ed,
              float* __restrict__ ws)
{
  const int blk = blockIdx.x, t = threadIdx.x;
  if (blk >= 1024) {                      // zeroing blocks: 264 of them
    int idx = (blk - 1024) * 256 + t;     // float4 index
    if (idx < WS_ZERO_F4)
      *(float4*)(ws + WS_ZERO_BASE + idx * 4) = make_float4(0.f, 0.f, 0.f, 0.f);
    return;
  }
  int g = blk * 256 + t;
  int row = g >> 5, o = g & 31;
  bool sup = row < (B_ * S_);
  int r = sup ? row : row - B_ * S_;
  const float* x  = (sup ? x_s : x_d) + r * 32;
  const float* W1 = sup ? W_ss : W_dd;
  const float* W2 = sup ? W_es : W_ed;
  const float* bb = sup ? b_ss : b_dd;
  float xr[32];
#pragma unroll
  for (int k = 0; k < 8; k++)
    *(float4*)&xr[4*k] = *(const float4*)(x + 4*k);
  float acc1 = bb[o], acc2 = 0.f;
#pragma unroll
  for (int e = 0; e < 32; e++) {
    acc1 += xr[e] * W1[o*32 + e];
    acc2 += xr[e] * W2[o*32 + e];
  }
  ws[(sup ? WS_BASES : WS_BASED) + r*32 + o] = acc1;
  ws[(sup ? WS_PES   : WS_PED  ) + r*32 + o] = acc2;
}

// ---------------- kernel 1: single pass over x_e ----------------
// Block = (s-tile st, d-half, b). Thread t owns d = half*256 + t for the whole
// kernel; iterates the tile's 8 s values. XOR-swizzled 32KB LDS tile gives
// fully coalesced global loads/stores and conflict-free b128 LDS row access.
__global__ __launch_bounds__(256, 4)
void k1_main(const float* __restrict__ x_e,
             const float* __restrict__ a_se_w, const float* __restrict__ a_se_b,
             const float* __restrict__ a_de_w, const float* __restrict__ a_de_b,
             const float* __restrict__ W_ee, const float* __restrict__ b_ee,
             float* __restrict__ ws,
             float* __restrict__ out)
{
  __shared__ float tile[256 * 32];        // 32 KB, xor-swizzled rows
  __shared__ float us[TS * 33];           // [si][e(32)+z(1)]

  const int t = threadIdx.x;
  const int st = blockIdx.x, half = blockIdx.y, b = blockIdx.z;
  const int s0 = st * TS;
  const int d_own = half * 256 + t;

  for (int i = t; i < TS * 33; i += 256) us[i] = 0.f;

  float pd[32];                            // peD[d_own][:] cached in regs
  const float* peD = ws + WS_PED + ((b * D_ + d_own) << 5);
#pragma unroll
  for (int k = 0; k < 8; k++)
    *(float4*)&pd[4*k] = *(const float4*)(peD + 4*k);

  float ud[32];
#pragma unroll
  for (int e = 0; e < 32; e++) ud[e] = 0.f;
  float zd = 0.f;
  const float asb = a_se_b[0], adb = a_de_b[0];

  __syncthreads();

#pragma unroll 1
  for (int si = 0; si < TS; si++) {
    const int s = s0 + si;
    const float* src = x_e + (((size_t)(b * S_ + s) * D_ + half * 256) << 5);

    // in-sweep: fully coalesced global -> LDS (swizzled)
#pragma unroll
    for (int w = 0; w < 8; w++) {
      const int g = w * 256 + t;
      const int r = g >> 3, q = g & 7;
      *(float4*)&tile[r*32 + ((q ^ (r & 7)) << 2)] = *(const float4*)(src + g*4);
    }
    __syncthreads();

    // own row -> regs (conflict-free b128)
    float x[32];
#pragma unroll
    for (int q = 0; q < 8; q++)
      *(float4*)&x[4*q] = *(const float4*)&tile[t*32 + ((q ^ (t & 7)) << 2)];

    // logits (uniform a-vectors -> SGPR broadcast)
    float ls = asb, ld2 = adb;
#pragma unroll
    for (int e = 0; e < 32; e++) {
      ls  += x[e] * a_se_w[e];
      ld2 += x[e] * a_de_w[e];
    }
    float es = __expf(ls), ed = __expf(ld2);

    // u_d: pure register accumulation (thread owns d)
    zd += ed;
#pragma unroll
    for (int e = 0; e < 32; e++) ud[e] += ed * x[e];

    // u_s: lane-rotated LDS atomics (2-way max)
#pragma unroll
    for (int k = 0; k < 32; k++) {
      int e = (t + k) & 31;
      atomicAdd(&us[si*33 + e], es * x[e]);
    }
    // Z_s: wave butterfly then one atomic per wave
    float v = es;
#pragma unroll
    for (int off = 32; off > 0; off >>= 1) v += __shfl_xor(v, off);
    if ((t & 63) == 0) atomicAdd(&us[si*33 + 32], v);

    // h_e: 32x32 projection, W_ee uniform -> SGPR-broadcast FMA
    const float* peS = ws + WS_PES + ((b * S_ + s) << 5);
#pragma unroll
    for (int oq = 0; oq < 8; oq++) {
      float a0 = 0.f, a1 = 0.f, a2 = 0.f, a3 = 0.f;
#pragma unroll
      for (int e = 0; e < 32; e++) {
        a0 += x[e] * W_ee[(4*oq+0)*32 + e];
        a1 += x[e] * W_ee[(4*oq+1)*32 + e];
        a2 += x[e] * W_ee[(4*oq+2)*32 + e];
        a3 += x[e] * W_ee[(4*oq+3)*32 + e];
      }
      float4 r4;
      r4.x = a0 + b_ee[4*oq+0] + peS[4*oq+0] + pd[4*oq+0];
      r4.y = a1 + b_ee[4*oq+1] + peS[4*oq+1] + pd[4*oq+1];
      r4.z = a2 + b_ee[4*oq+2] + peS[4*oq+2] + pd[4*oq+2];
      r4.w = a3 + b_ee[4*oq+3] + peS[4*oq+3] + pd[4*oq+3];
      *(float4*)&tile[t*32 + ((oq ^ (t & 7)) << 2)] = r4;   // in-place
    }
    __syncthreads();

    // out-sweep: fully coalesced LDS -> global
    float* dst = out + HE_OFF + (((size_t)(b * S_ + s) * D_ + half * 256) << 5);
#pragma unroll
    for (int w = 0; w < 8; w++) {
      const int g = w * 256 + t;
      const int r = g >> 3, q = g & 7;
      *(float4*)(dst + g*4) = *(const float4*)&tile[r*32 + ((q ^ (r & 7)) << 2)];
    }
    __syncthreads();   // protect tile for next phase's in-sweep
  }

  // flush u_d / Z_d (register partials -> global atomics)
  float* udp = ws + WS_UD + ((b * D_ + d_own) << 5);
#pragma unroll
  for (int e = 0; e < 32; e++) atomicAdd(udp + e, ud[e]);
  atomicAdd(ws + WS_ZD + b * D_ + d_own, zd);

  // flush u_s / Z_s (LDS partials -> global atomics)
  for (int i = t; i < TS * 33; i += 256) {
    int si = i / 33, j = i - si * 33;
    int srow = b * S_ + s0 + si;
    if (j < 32) atomicAdd(ws + WS_US + srow*32 + j, us[i]);
    else        atomicAdd(ws + WS_ZS + srow, us[i]);
  }
}

// ---------------- kernel 2: normalize + node-output projections ----------------
__global__ __launch_bounds__(256)
void k2_epi(const float* __restrict__ W_se, const float* __restrict__ W_de,
            const float* __restrict__ ws, float* __restrict__ out)
{
  int g = blockIdx.x * 256 + threadIdx.x;
  int row = g >> 5, o = g & 31;
  bool sup = row < B_ * S_;
  int r = sup ? row : row - B_ * S_;
  const float* u = ws + (sup ? WS_US : WS_UD) + r*32;
  float z = ws[(sup ? WS_ZS : WS_ZD) + r];
  const float* W = sup ? W_se : W_de;
  float dot = 0.f;
#pragma unroll
  for (int e = 0; e < 32; e++) dot += W[o*32 + e] * u[e];
  float base = ws[(sup ? WS_BASES : WS_BASED) + r*32 + o];
  out[(sup ? HS_OFF : HD_OFF) + r*32 + o] = base + dot / z;
}

extern "C" void kernel_launch(void* const* d_in, const int* in_sizes, int n_in,
                              void* d_out, int out_size, void* d_ws, size_t ws_size,
                              hipStream_t stream)
{
  const float* x_s    = (const float*)d_in[0];
  const float* x_d    = (const float*)d_in[1];
  const float* x_e    = (const float*)d_in[2];
  const float* W_ss   = (const float*)d_in[3];
  const float* b_ss   = (const float*)d_in[4];
  const float* W_se   = (const float*)d_in[5];
  const float* a_se_w = (const float*)d_in[6];
  const float* a_se_b = (const float*)d_in[7];
  const float* W_dd   = (const float*)d_in[8];
  const float* b_dd   = (const float*)d_in[9];
  const float* W_de   = (const float*)d_in[10];
  const float* a_de_w = (const float*)d_in[11];
  const float* a_de_b = (const float*)d_in[12];
  const float* W_ee   = (const float*)d_in[13];
  const float* b_ee   = (const float*)d_in[14];
  const float* W_es   = (const float*)d_in[15];
  const float* W_ed   = (const float*)d_in[16];
  float* out = (float*)d_out;
  float* ws  = (float*)d_ws;

  hipLaunchKernelGGL(k0_nodes, dim3(1288), dim3(256), 0, stream,
                     x_s, x_d, W_ss, b_ss, W_dd, b_dd, W_es, W_ed, ws);
  hipLaunchKernelGGL(k1_main, dim3(64, 2, B_), dim3(256), 0, stream,
                     x_e, a_se_w, a_se_b, a_de_w, a_de_b, W_ee, b_ee, ws, out);
  hipLaunchKernelGGL(k2_epi, dim3(1024), dim3(256), 0, stream,
                     W_se, W_de, ws, out);
}